// Round 1
// baseline (1158.304 us; speedup 1.0000x reference)
//
#include <hip/hip_runtime.h>
#include <stdint.h>
#include <math.h>

#define CONF_THR  0.005f
#define SCORE_THRf 0.05f
#define IOU_THR   0.45f
#define TOPK      4096
#define MAXDET    100
#define NCLS      80
#define BCAP      8192   // boundary-bucket list capacity per image
#define NHIST     8192
#define NIMG      16
#define NLOC      7581   // 361 + 1444 + 5776 locations per image

// anchor half-widths/heights per (level, anchor): exact floats
__constant__ float c_half[3][3][2] = {
  {{58.0f, 45.0f}, {78.0f, 99.0f}, {186.5f, 163.0f}},   // stride 32
  {{15.0f, 30.5f}, {31.0f, 22.5f}, {29.5f, 59.5f}},     // stride 16
  {{5.0f, 6.5f},  {8.0f, 15.0f},  {16.5f, 11.5f}},      // stride 8
};

__device__ __forceinline__ float sigmoidf_(float x) {
  return 1.0f / (1.0f + expf(-x));
}

// ---------------- K1: per-image 8192-bucket histogram of score float bits ---------
__global__ void k_hist(const float* __restrict__ p0, const float* __restrict__ p1,
                       const float* __restrict__ p2, unsigned* __restrict__ hist) {
  __shared__ unsigned lh[NHIST];
  const int b = blockIdx.y;
  for (int i = threadIdx.x; i < NHIST; i += blockDim.x) lh[i] = 0;
  __syncthreads();
  const int u = blockIdx.x * blockDim.x + threadIdx.x;
  if (u < NLOC) {
    const float* p; int HW, hw;
    if (u < 361)       { p = p0; HW = 361;  hw = u; }
    else if (u < 1805) { p = p1; HW = 1444; hw = u - 361; }
    else               { p = p2; HW = 5776; hw = u - 1805; }
    p += (size_t)b * 255 * HW + hw;
    for (int a = 0; a < 3; ++a) {
      float obj = sigmoidf_(p[(size_t)(a * 85 + 4) * HW]);
      if (obj >= CONF_THR) {
        for (int c = 0; c < NCLS; ++c) {
          float cs = sigmoidf_(p[(size_t)(a * 85 + 5 + c) * HW]);
          if (cs > SCORE_THRf) {
            float sc = __fmul_rn(cs, obj);           // matches cls * obj[:,None]
            unsigned bkt = __float_as_uint(sc) >> 17; // monotonic for positive floats
            atomicAdd(&lh[bkt], 1u);
          }
        }
      }
    }
  }
  __syncthreads();
  unsigned* gh = hist + (size_t)b * NHIST;
  for (int i = threadIdx.x; i < NHIST; i += blockDim.x)
    if (lh[i]) atomicAdd(&gh[i], lh[i]);
}

// ---------------- K2: find boundary bucket (largest b with cumAbove < TOPK <= cum incl) --
__global__ void k_scan(const unsigned* __restrict__ hist, int* __restrict__ bb1) {
  __shared__ unsigned h[NHIST];
  __shared__ unsigned csum[256];
  const int b = blockIdx.x;
  const unsigned* gh = hist + (size_t)b * NHIST;
  for (int i = threadIdx.x; i < NHIST; i += 256) h[i] = gh[i];
  __syncthreads();
  unsigned s = 0;
  for (int j = 0; j < 32; ++j) s += h[threadIdx.x * 32 + j];
  csum[threadIdx.x] = s;
  __syncthreads();
  if (threadIdx.x == 0) {
    unsigned acc = 0; int found = -1;
    for (int c2 = 255; c2 >= 0; --c2) {
      if (acc + csum[c2] >= TOPK) {
        for (int k2 = c2 * 32 + 31; k2 >= c2 * 32; --k2) {
          if (acc + h[k2] >= TOPK) { found = k2; break; }
          acc += h[k2];
        }
        break;
      } else acc += csum[c2];
    }
    bb1[b] = found;  // -1 => fewer than TOPK valid, take all
  }
}

// ---------------- K3: recompute scores, emit winner keys / boundary-bucket keys -----
__global__ void k_collect(const float* __restrict__ p0, const float* __restrict__ p1,
                          const float* __restrict__ p2, const int* __restrict__ bb1v,
                          unsigned* __restrict__ candCount, unsigned* __restrict__ bCount,
                          unsigned long long* __restrict__ candKeys,
                          unsigned long long* __restrict__ blist) {
  const int b = blockIdx.y;
  const int Bb1 = bb1v[b];
  const int u = blockIdx.x * blockDim.x + threadIdx.x;
  if (u >= NLOC) return;
  const float* p; int HW, hw, nstart;
  if (u < 361)       { p = p0; HW = 361;  hw = u;        nstart = 0; }
  else if (u < 1805) { p = p1; HW = 1444; hw = u - 361;  nstart = 1083; }
  else               { p = p2; HW = 5776; hw = u - 1805; nstart = 5415; }
  p += (size_t)b * 255 * HW + hw;
  unsigned long long* ck = candKeys + (size_t)b * TOPK;
  unsigned long long* bl = blist + (size_t)b * BCAP;
  for (int a = 0; a < 3; ++a) {
    float obj = sigmoidf_(p[(size_t)(a * 85 + 4) * HW]);
    if (obj < CONF_THR) continue;
    const int n = nstart + hw * 3 + a;
    for (int c = 0; c < NCLS; ++c) {
      float cs = sigmoidf_(p[(size_t)(a * 85 + 5 + c) * HW]);
      if (cs <= SCORE_THRf) continue;
      float sc = __fmul_rn(cs, obj);
      unsigned bits = __float_as_uint(sc);
      int bkt = (int)(bits >> 17);
      unsigned idx = (unsigned)n * 80u + (unsigned)c;
      // key: (orderable score bits) << 32 | (idx inverted) => sort desc == (score desc, idx asc)
      unsigned long long key =
          ((unsigned long long)(bits ^ 0x80000000u) << 32) | (unsigned long long)(0xFFFFFFFFu - idx);
      if (bkt > Bb1) {
        unsigned pos = atomicAdd(&candCount[b], 1u);
        if (pos < TOPK) ck[pos] = key;
      } else if (bkt == Bb1) {
        unsigned pos = atomicAdd(&bCount[b], 1u);
        if (pos < BCAP) bl[pos] = key;
      }
    }
  }
}

// ---------------- bitonic helper (descending), in LDS ------------------------------
__device__ __forceinline__ void bitonic_desc(unsigned long long* sb, int p2, int nthr, int tid) {
  for (int k = 2; k <= p2; k <<= 1) {
    for (int j = k >> 1; j > 0; j >>= 1) {
      for (int i = tid; i < p2; i += nthr) {
        int ixj = i ^ j;
        if (ixj > i) {
          unsigned long long A = sb[i], B2 = sb[ixj];
          bool up = (i & k) == 0;
          if (up ? (A < B2) : (A > B2)) { sb[i] = B2; sb[ixj] = A; }
        }
      }
      __syncthreads();
    }
  }
}

// ---------------- K4: sort boundary list, append exactly what's needed, pad --------
__global__ void __launch_bounds__(256) k_bsort(const unsigned* __restrict__ candCount,
                                               const unsigned* __restrict__ bCount,
                                               unsigned long long* __restrict__ candKeys,
                                               const unsigned long long* __restrict__ blist) {
  __shared__ unsigned long long sb[BCAP];  // 64 KiB
  const int b = blockIdx.x;
  unsigned C1 = candCount[b]; if (C1 > TOPK) C1 = TOPK;
  unsigned m = bCount[b];     if (m > BCAP) m = BCAP;
  int need = TOPK - (int)C1;
  int take = need > 0 ? (need < (int)m ? need : (int)m) : 0;
  unsigned long long* ck = candKeys + (size_t)b * TOPK;
  const unsigned long long* bl = blist + (size_t)b * BCAP;
  if (take > 0) {
    int p2 = 1; while (p2 < (int)m) p2 <<= 1;
    for (int i = threadIdx.x; i < p2; i += 256) sb[i] = (i < (int)m) ? bl[i] : 0ull;
    __syncthreads();
    bitonic_desc(sb, p2, 256, threadIdx.x);
    for (int i = threadIdx.x; i < take; i += 256) ck[C1 + i] = sb[i];
  }
  for (int i = (int)C1 + take + threadIdx.x; i < TOPK; i += 256) ck[i] = 0ull;  // dead pads
}

// ---------------- K5: full 4096 sort (replicates top_k order), decode boxes, max_coord --
__global__ void __launch_bounds__(512) k_csort_decode(
    const float* __restrict__ p0, const float* __restrict__ p1, const float* __restrict__ p2,
    unsigned long long* __restrict__ candKeys, float4* __restrict__ boxS,
    float* __restrict__ maxcv) {
  __shared__ unsigned long long sb[TOPK];  // 32 KiB
  __shared__ float red[512];
  const int b = blockIdx.x;
  unsigned long long* ck = candKeys + (size_t)b * TOPK;
  for (int i = threadIdx.x; i < TOPK; i += 512) sb[i] = ck[i];
  __syncthreads();
  bitonic_desc(sb, TOPK, 512, threadIdx.x);
  for (int i = threadIdx.x; i < TOPK; i += 512) ck[i] = sb[i];

  float lmax = -INFINITY;
  float4* bs = boxS + (size_t)b * TOPK;
  for (int i = threadIdx.x; i < TOPK; i += 512) {
    unsigned long long key = sb[i];
    float4 bx = make_float4(0.f, 0.f, 0.f, 0.f);
    float contrib = 0.0f;  // non-finite rows contribute 0.0 (matches jnp.where)
    if (key != 0ull) {
      unsigned idx = 0xFFFFFFFFu - (unsigned)(key & 0xFFFFFFFFull);
      int n = (int)(idx / 80u);
      const float* p; int HW, W, nstart, L; float fs;
      if (n < 1083)      { p = p0; HW = 361;  W = 19; nstart = 0;    fs = 32.f; L = 0; }
      else if (n < 5415) { p = p1; HW = 1444; W = 38; nstart = 1083; fs = 16.f; L = 1; }
      else               { p = p2; HW = 5776; W = 76; nstart = 5415; fs = 8.f;  L = 2; }
      int r = n - nstart; int hw = r / 3; int a = r % 3;
      int gx = hw % W;    int gy = hw / W;
      const float* q = p + (size_t)b * 255 * HW + hw;
      float tx = q[(size_t)(a * 85 + 0) * HW];
      float ty = q[(size_t)(a * 85 + 1) * HW];
      float tw = q[(size_t)(a * 85 + 2) * HW];
      float th = q[(size_t)(a * 85 + 3) * HW];
      float acx = __fadd_rn((float)gx * fs, 0.5f * fs);  // exact anchor center
      float acy = __fadd_rn((float)gy * fs, 0.5f * fs);
      float sx = sigmoidf_(tx), sy = sigmoidf_(ty);
      // centers = anchor_center + (sig - 0.5) * stride  (no fma contraction)
      float cx = __fadd_rn(acx, __fmul_rn(__fsub_rn(sx, 0.5f), fs));
      float cy = __fadd_rn(acy, __fmul_rn(__fsub_rn(sy, 0.5f), fs));
      float wx = __fmul_rn(c_half[L][a][0], expf(tw));
      float wy = __fmul_rn(c_half[L][a][1], expf(th));
      bx.x = __fsub_rn(cx, wx); bx.y = __fsub_rn(cy, wy);
      bx.z = __fadd_rn(cx, wx); bx.w = __fadd_rn(cy, wy);
      contrib = fmaxf(fmaxf(bx.x, bx.y), fmaxf(bx.z, bx.w));
    }
    bs[i] = bx;
    lmax = fmaxf(lmax, contrib);
  }
  red[threadIdx.x] = lmax;
  __syncthreads();
  for (int s2 = 256; s2 > 0; s2 >>= 1) {
    if (threadIdx.x < s2) red[threadIdx.x] = fmaxf(red[threadIdx.x], red[threadIdx.x + s2]);
    __syncthreads();
  }
  if (threadIdx.x == 0) maxcv[b] = red[0];
}

// ---------------- K6: lazy greedy NMS, one wave per image --------------------------
__global__ void __launch_bounds__(64) k_nms(const unsigned long long* __restrict__ candKeys,
                                            const float4* __restrict__ boxS,
                                            const float* __restrict__ maxcv,
                                            float* __restrict__ out) {
  const int b = blockIdx.x;
  const int lane = threadIdx.x;
  float* dets = out + (size_t)b * (MAXDET * 5);
  float* lbls = out + (size_t)NIMG * MAXDET * 5 + (size_t)b * MAXDET;
  for (int i = lane; i < MAXDET; i += 64) {
    dets[i * 5 + 0] = 0.f; dets[i * 5 + 1] = 0.f; dets[i * 5 + 2] = 0.f;
    dets[i * 5 + 3] = 0.f; dets[i * 5 + 4] = 0.f;
    lbls[i] = -1.0f;
  }
  __syncthreads();
  const float mc1 = __fadd_rn(maxcv[b], 1.0f);
  const unsigned long long* ck = candKeys + (size_t)b * TOPK;
  const float4* bs = boxS + (size_t)b * TOPK;
  float pbx1[2], pby1[2], pbx2[2], pby2[2], parea[2];
  int P = 0;
  bool done = false;
  for (int base = 0; base < TOPK && !done; base += 64) {
    const int e = base + lane;
    unsigned long long key = ck[e];
    float score = -INFINITY; int c = 0;
    float4 bx = bs[e];
    if (key) {
      unsigned mb = (unsigned)(key >> 32);
      score = __uint_as_float(mb ^ 0x80000000u);
      unsigned idx = 0xFFFFFFFFu - (unsigned)(key & 0xFFFFFFFFull);
      c = (int)(idx % 80u);
    }
    // nms-space box: cbox + label*(max_coord+1), same op order as reference
    float off = __fmul_rn((float)c, mc1);
    float nx1 = __fadd_rn(bx.x, off), ny1 = __fadd_rn(bx.y, off);
    float nx2 = __fadd_rn(bx.z, off), ny2 = __fadd_rn(bx.w, off);
    for (int t = 0; t < 64; ++t) {
      float s_e = __shfl(score, t);
      if (!(s_e > 0.0f)) { done = true; break; }  // sorted desc: rest are dead/zero rows
      float ex1 = __shfl(nx1, t), ey1 = __shfl(ny1, t);
      float ex2 = __shfl(nx2, t), ey2 = __shfl(ny2, t);
      float ea = __fmul_rn(__fsub_rn(ex2, ex1), __fsub_rn(ey2, ey1));  // a2
      bool sup = false;
      #pragma unroll
      for (int k2 = 0; k2 < 2; ++k2) {
        int pi = k2 * 64 + lane;
        if (pi < P) {
          float tlx = fmaxf(pbx1[k2], ex1), tly = fmaxf(pby1[k2], ey1);
          float brx = fminf(pbx2[k2], ex2), bry = fminf(pby2[k2], ey2);
          float iw = fmaxf(__fsub_rn(brx, tlx), 0.0f);
          float ih = fmaxf(__fsub_rn(bry, tly), 0.0f);
          float inter = __fmul_rn(iw, ih);
          // a1 + a2 - inter + 1e-12 with reference op order (a1 = picked area)
          float denom = __fadd_rn(__fsub_rn(__fadd_rn(parea[k2], ea), inter), 1e-12f);
          float iou = __fdiv_rn(inter, denom);
          if (iou > IOU_THR) sup = true;
        }
      }
      if (!__any(sup)) {
        // pick: broadcast original box + label, lane0 writes det row
        float cx1 = __shfl(bx.x, t), cy1 = __shfl(bx.y, t);
        float cx2 = __shfl(bx.z, t), cy2 = __shfl(bx.w, t);
        int   ce  = __shfl(c, t);
        if (lane == (P & 63)) {
          int slot = P >> 6;
          pbx1[slot] = ex1; pby1[slot] = ey1; pbx2[slot] = ex2; pby2[slot] = ey2;
          parea[slot] = ea;
        }
        if (lane == 0) {
          dets[P * 5 + 0] = cx1; dets[P * 5 + 1] = cy1;
          dets[P * 5 + 2] = cx2; dets[P * 5 + 3] = cy2;
          dets[P * 5 + 4] = s_e;
          lbls[P] = (float)ce;
        }
        ++P;
        if (P == MAXDET) { done = true; break; }
      }
    }
  }
}

// ---------------- launch -----------------------------------------------------------
extern "C" void kernel_launch(void* const* d_in, const int* in_sizes, int n_in,
                              void* d_out, int out_size, void* d_ws, size_t ws_size,
                              hipStream_t stream) {
  const float* p0 = (const float*)d_in[0];  // [16,255,19,19]
  const float* p1 = (const float*)d_in[1];  // [16,255,38,38]
  const float* p2 = (const float*)d_in[2];  // [16,255,76,76]
  float* out = (float*)d_out;               // 8000 det floats + 1600 label floats
  char* ws = (char*)d_ws;

  // ws layout (all 256B-aligned offsets)
  unsigned* hist = (unsigned*)ws;                                   // 16*8192*4  = 524288
  unsigned* candCount = (unsigned*)(ws + 524288);                   // 16 u32
  unsigned* bCount = candCount + 16;                                // 16 u32
  int* bb1 = (int*)(bCount + 16);                                   // 16 i32
  float* maxcv = (float*)(bb1 + 16);                                // 16 f32
  unsigned long long* candKeys = (unsigned long long*)(ws + 524544);   // 16*4096*8 = 524288
  unsigned long long* blist = (unsigned long long*)(ws + 1048832);     // 16*8192*8 = 1048576
  float4* boxS = (float4*)(ws + 2097408);                              // 16*4096*16 = 1048576
  // total ws used: 3,145,984 bytes

  hipMemsetAsync(ws, 0, 524544, stream);  // hist + counters

  dim3 gloc((NLOC + 255) / 256, NIMG);
  k_hist<<<gloc, 256, 0, stream>>>(p0, p1, p2, hist);
  k_scan<<<NIMG, 256, 0, stream>>>(hist, bb1);
  k_collect<<<gloc, 256, 0, stream>>>(p0, p1, p2, bb1, candCount, bCount, candKeys, blist);
  k_bsort<<<NIMG, 256, 0, stream>>>(candCount, bCount, candKeys, blist);
  k_csort_decode<<<NIMG, 512, 0, stream>>>(p0, p1, p2, candKeys, boxS, maxcv);
  k_nms<<<NIMG, 64, 0, stream>>>(candKeys, boxS, maxcv, out);
}

// Round 3
// 449.963 us; speedup vs baseline: 2.5742x; 2.5742x over previous
//
#include <hip/hip_runtime.h>
#include <stdint.h>
#include <math.h>

#define CONF_THR   0.005f
#define SCORE_THRf 0.05f
#define IOU_THR    0.45f
#define TOPK       4096
#define MAXDET     100
#define NHIST      8192
#define NIMG       16
#define BCAP       8192
#define NSLICE     27          // chunks per image: 3 anchors * (6 + 2 + 1)
#define NBLK       (NIMG * NSLICE)
#define LCAP       1024        // per-block LDS emission buffer

// anchor half-widths/heights per (level, anchor): exact floats
__constant__ float c_half[3][3][2] = {
  {{58.0f, 45.0f}, {78.0f, 99.0f}, {186.5f, 163.0f}},   // stride 32
  {{15.0f, 30.5f}, {31.0f, 22.5f}, {29.5f, 59.5f}},     // stride 16
  {{5.0f, 6.5f},  {8.0f, 15.0f},  {16.5f, 11.5f}},      // stride 8
};

__device__ __forceinline__ float sigmoidf_(float x) {
  return 1.0f / (1.0f + expf(-x));
}

// Enumerate all valid (score, flat-idx) pairs owned by this block.
// Block bx = b*27 + r;  r<18: map2 (a=r/6, chunk=r%6), r<24: map1, else map0.
// Thread t covers locations hw0..hw0+3 (float4 rows for map1/map2; map0 scalar).
template <typename F>
__device__ __forceinline__ void enumerate_scores(
    const float* __restrict__ p0, const float* __restrict__ p1,
    const float* __restrict__ p2, int bx, int tid, F&& emit) {
  const int b = bx / NSLICE;
  const int r = bx % NSLICE;
  int mi, a, h0;
  if (r < 18)      { mi = 2; a = r / 6;        h0 = (r % 6) * 1024; }
  else if (r < 24) { mi = 1; a = (r - 18) >> 1; h0 = ((r - 18) & 1) * 1024; }
  else             { mi = 0; a = r - 24;        h0 = 0; }
  const float* p; int HW, nstart;
  if (mi == 2)      { p = p2; HW = 5776; nstart = 5415; }
  else if (mi == 1) { p = p1; HW = 1444; nstart = 1083; }
  else              { p = p0; HW = 361;  nstart = 0; }
  const int hw0 = h0 + tid * 4;
  if (hw0 >= HW) return;   // no barriers inside this function: early return is safe
  const float* q = p + (size_t)b * 255 * HW;
  const float* orow = q + (size_t)(a * 85 + 4) * HW;

  float so[4]; bool ov[4] = {false, false, false, false};
  if (mi != 0) {                      // HW % 4 == 0 and rows 16B-aligned
    float4 o = *(const float4*)(orow + hw0);
    so[0] = sigmoidf_(o.x); so[1] = sigmoidf_(o.y);
    so[2] = sigmoidf_(o.z); so[3] = sigmoidf_(o.w);
    #pragma unroll
    for (int k = 0; k < 4; ++k) ov[k] = so[k] >= CONF_THR;
  } else {
    #pragma unroll
    for (int k = 0; k < 4; ++k)
      if (hw0 + k < HW) { so[k] = sigmoidf_(orow[hw0 + k]); ov[k] = so[k] >= CONF_THR; }
  }

  for (int c = 0; c < 80; ++c) {
    const float* crow = q + (size_t)(a * 85 + 5 + c) * HW;
    float cv[4];
    if (mi != 0) {
      float4 v = *(const float4*)(crow + hw0);
      cv[0] = v.x; cv[1] = v.y; cv[2] = v.z; cv[3] = v.w;
    } else {
      #pragma unroll
      for (int k = 0; k < 4; ++k) cv[k] = (hw0 + k < HW) ? crow[hw0 + k] : -100.0f;
    }
    #pragma unroll
    for (int k = 0; k < 4; ++k) {
      if (!ov[k]) continue;
      float cs = sigmoidf_(cv[k]);
      if (cs > SCORE_THRf) {
        float sc = __fmul_rn(cs, so[k]);             // matches cls * obj[:,None]
        unsigned bits = __float_as_uint(sc);
        unsigned idx = (unsigned)((nstart + (hw0 + k) * 3 + a) * 80 + c);
        emit(bits, idx);
      }
    }
  }
}

// ---------------- K1: per-block private histogram (or atomic-merge fallback) -------
template <bool PRIV>
__global__ void __launch_bounds__(256) k_hist(const float* __restrict__ p0,
                                              const float* __restrict__ p1,
                                              const float* __restrict__ p2,
                                              unsigned* __restrict__ outHist) {
  __shared__ unsigned lh[NHIST];
  for (int i = threadIdx.x; i < NHIST; i += 256) lh[i] = 0;
  __syncthreads();
  enumerate_scores(p0, p1, p2, blockIdx.x, threadIdx.x,
                   [&](unsigned bits, unsigned) { atomicAdd(&lh[bits >> 17], 1u); });
  __syncthreads();
  if (PRIV) {
    unsigned* dst = outHist + (size_t)blockIdx.x * NHIST;          // private slice
    for (int i = threadIdx.x; i < NHIST; i += 256) dst[i] = lh[i];
  } else {
    unsigned* dst = outHist + (size_t)(blockIdx.x / NSLICE) * NHIST; // merged (memset 0)
    for (int i = threadIdx.x; i < NHIST; i += 256) if (lh[i]) atomicAdd(&dst[i], lh[i]);
  }
}

// ---------------- K1b: merge private histograms -> per-image histogram -------------
__global__ void __launch_bounds__(256) k_merge(const unsigned* __restrict__ priv,
                                               unsigned* __restrict__ merged) {
  const int b = blockIdx.y;
  const int u = blockIdx.x * 256 + threadIdx.x;   // bucket
  const unsigned* base = priv + (size_t)b * NSLICE * NHIST + u;
  unsigned s = 0;
  #pragma unroll
  for (int sl = 0; sl < NSLICE; ++sl) s += base[(size_t)sl * NHIST];
  merged[(size_t)b * NHIST + u] = s;
}

// ---------------- K2: find boundary bucket -----------------------------------------
__global__ void k_scan(const unsigned* __restrict__ hist, int* __restrict__ bb1) {
  __shared__ unsigned h[NHIST];
  __shared__ unsigned csum[256];
  const int b = blockIdx.x;
  const unsigned* gh = hist + (size_t)b * NHIST;
  for (int i = threadIdx.x; i < NHIST; i += 256) h[i] = gh[i];
  __syncthreads();
  unsigned s = 0;
  for (int j = 0; j < 32; ++j) s += h[threadIdx.x * 32 + j];
  csum[threadIdx.x] = s;
  __syncthreads();
  if (threadIdx.x == 0) {
    unsigned acc = 0; int found = -1;
    for (int c2 = 255; c2 >= 0; --c2) {
      if (acc + csum[c2] >= TOPK) {
        for (int k2 = c2 * 32 + 31; k2 >= c2 * 32; --k2) {
          if (acc + h[k2] >= TOPK) { found = k2; break; }
          acc += h[k2];
        }
        break;
      } else acc += csum[c2];
    }
    bb1[b] = found;  // -1 => fewer than TOPK valid, take all
  }
}

// ---------------- K3: collect winner / boundary keys via LDS buffers ---------------
__global__ void __launch_bounds__(256) k_collect(const float* __restrict__ p0,
                                                 const float* __restrict__ p1,
                                                 const float* __restrict__ p2,
                                                 const int* __restrict__ bb1v,
                                                 unsigned* __restrict__ candCount,
                                                 unsigned* __restrict__ bCount,
                                                 unsigned long long* __restrict__ candKeys,
                                                 unsigned long long* __restrict__ blist) {
  __shared__ unsigned long long wbuf[LCAP];
  __shared__ unsigned long long bbuf[LCAP];
  __shared__ unsigned cnt2[2];
  __shared__ unsigned base2[2];
  const int b = blockIdx.x / NSLICE;
  if (threadIdx.x < 2) cnt2[threadIdx.x] = 0;
  __syncthreads();
  const int Bb1 = bb1v[b];
  unsigned long long* ckg = candKeys + (size_t)b * TOPK;
  unsigned long long* blg = blist + (size_t)b * BCAP;

  enumerate_scores(p0, p1, p2, blockIdx.x, threadIdx.x,
    [&](unsigned bits, unsigned idx) {
      int bkt = (int)(bits >> 17);
      if (bkt < Bb1) return;
      unsigned long long key = ((unsigned long long)(bits ^ 0x80000000u) << 32) |
                               (unsigned long long)(0xFFFFFFFFu - idx);
      if (bkt > Bb1) {
        unsigned pos = atomicAdd(&cnt2[0], 1u);
        if (pos < LCAP) wbuf[pos] = key;
        else { unsigned g = atomicAdd(&candCount[b], 1u); if (g < TOPK) ckg[g] = key; }
      } else {
        unsigned pos = atomicAdd(&cnt2[1], 1u);
        if (pos < LCAP) bbuf[pos] = key;
        else { unsigned g = atomicAdd(&bCount[b], 1u); if (g < BCAP) blg[g] = key; }
      }
    });
  __syncthreads();
  unsigned wn = min(cnt2[0], (unsigned)LCAP);
  unsigned bn = min(cnt2[1], (unsigned)LCAP);
  if (threadIdx.x == 0) base2[0] = wn ? atomicAdd(&candCount[b], wn) : 0u;
  if (threadIdx.x == 1) base2[1] = bn ? atomicAdd(&bCount[b], bn) : 0u;
  __syncthreads();
  for (unsigned i = threadIdx.x; i < wn; i += 256) {
    unsigned g = base2[0] + i; if (g < TOPK) ckg[g] = wbuf[i];
  }
  for (unsigned i = threadIdx.x; i < bn; i += 256) {
    unsigned g = base2[1] + i; if (g < BCAP) blg[g] = bbuf[i];
  }
}

// ---------------- bitonic helper (descending), in LDS ------------------------------
__device__ __forceinline__ void bitonic_desc(unsigned long long* sb, int p2, int nthr, int tid) {
  for (int k = 2; k <= p2; k <<= 1) {
    for (int j = k >> 1; j > 0; j >>= 1) {
      for (int i = tid; i < p2; i += nthr) {
        int ixj = i ^ j;
        if (ixj > i) {
          unsigned long long A = sb[i], B2 = sb[ixj];
          bool up = (i & k) == 0;
          if (up ? (A < B2) : (A > B2)) { sb[i] = B2; sb[ixj] = A; }
        }
      }
      __syncthreads();
    }
  }
}

// ---------------- K4: sort boundary list, append what's needed, pad ----------------
__global__ void __launch_bounds__(1024) k_bsort(const unsigned* __restrict__ candCount,
                                                const unsigned* __restrict__ bCount,
                                                unsigned long long* __restrict__ candKeys,
                                                const unsigned long long* __restrict__ blist) {
  __shared__ unsigned long long sb[BCAP];  // 64 KiB
  const int b = blockIdx.x;
  unsigned C1 = candCount[b]; if (C1 > TOPK) C1 = TOPK;
  unsigned m = bCount[b];     if (m > BCAP) m = BCAP;
  int need = TOPK - (int)C1;
  int take = need > 0 ? (need < (int)m ? need : (int)m) : 0;
  unsigned long long* ck = candKeys + (size_t)b * TOPK;
  const unsigned long long* bl = blist + (size_t)b * BCAP;
  if (take > 0) {
    int p2 = 1; while (p2 < (int)m) p2 <<= 1;
    for (int i = threadIdx.x; i < p2; i += 1024) sb[i] = (i < (int)m) ? bl[i] : 0ull;
    __syncthreads();
    bitonic_desc(sb, p2, 1024, threadIdx.x);
    for (int i = threadIdx.x; i < take; i += 1024) ck[C1 + i] = sb[i];
  }
  for (int i = (int)C1 + take + threadIdx.x; i < TOPK; i += 1024) ck[i] = 0ull;
}

// ---------------- K5: full 4096 sort, decode boxes, max_coord ----------------------
__global__ void __launch_bounds__(1024) k_csort_decode(
    const float* __restrict__ p0, const float* __restrict__ p1, const float* __restrict__ p2,
    unsigned long long* __restrict__ candKeys, float4* __restrict__ boxS,
    float* __restrict__ maxcv) {
  __shared__ unsigned long long sb[TOPK];  // 32 KiB
  __shared__ float red[1024];
  const int b = blockIdx.x;
  unsigned long long* ck = candKeys + (size_t)b * TOPK;
  for (int i = threadIdx.x; i < TOPK; i += 1024) sb[i] = ck[i];
  __syncthreads();
  bitonic_desc(sb, TOPK, 1024, threadIdx.x);
  for (int i = threadIdx.x; i < TOPK; i += 1024) ck[i] = sb[i];

  float lmax = -INFINITY;
  float4* bs = boxS + (size_t)b * TOPK;
  for (int i = threadIdx.x; i < TOPK; i += 1024) {
    unsigned long long key = sb[i];
    float4 bx = make_float4(0.f, 0.f, 0.f, 0.f);
    float contrib = 0.0f;  // dead rows contribute 0.0 (matches jnp.where)
    if (key != 0ull) {
      unsigned idx = 0xFFFFFFFFu - (unsigned)(key & 0xFFFFFFFFull);
      int n = (int)(idx / 80u);
      const float* p; int HW, W, nstart, L; float fs;
      if (n < 1083)      { p = p0; HW = 361;  W = 19; nstart = 0;    fs = 32.f; L = 0; }
      else if (n < 5415) { p = p1; HW = 1444; W = 38; nstart = 1083; fs = 16.f; L = 1; }
      else               { p = p2; HW = 5776; W = 76; nstart = 5415; fs = 8.f;  L = 2; }
      int r = n - nstart; int hw = r / 3; int a = r % 3;
      int gx = hw % W;    int gy = hw / W;
      const float* q = p + (size_t)b * 255 * HW + hw;
      float tx = q[(size_t)(a * 85 + 0) * HW];
      float ty = q[(size_t)(a * 85 + 1) * HW];
      float tw = q[(size_t)(a * 85 + 2) * HW];
      float th = q[(size_t)(a * 85 + 3) * HW];
      float acx = __fadd_rn((float)gx * fs, 0.5f * fs);  // exact anchor center
      float acy = __fadd_rn((float)gy * fs, 0.5f * fs);
      float sx = sigmoidf_(tx), sy = sigmoidf_(ty);
      float cx = __fadd_rn(acx, __fmul_rn(__fsub_rn(sx, 0.5f), fs));
      float cy = __fadd_rn(acy, __fmul_rn(__fsub_rn(sy, 0.5f), fs));
      float wx = __fmul_rn(c_half[L][a][0], expf(tw));
      float wy = __fmul_rn(c_half[L][a][1], expf(th));
      bx.x = __fsub_rn(cx, wx); bx.y = __fsub_rn(cy, wy);
      bx.z = __fadd_rn(cx, wx); bx.w = __fadd_rn(cy, wy);
      contrib = fmaxf(fmaxf(bx.x, bx.y), fmaxf(bx.z, bx.w));
    }
    bs[i] = bx;
    lmax = fmaxf(lmax, contrib);
  }
  red[threadIdx.x] = lmax;
  __syncthreads();
  for (int s2 = 512; s2 > 0; s2 >>= 1) {
    if (threadIdx.x < s2) red[threadIdx.x] = fmaxf(red[threadIdx.x], red[threadIdx.x + s2]);
    __syncthreads();
  }
  if (threadIdx.x == 0) maxcv[b] = red[0];
}

// ---------------- K6: lazy greedy NMS, one wave per image --------------------------
__global__ void __launch_bounds__(64) k_nms(const unsigned long long* __restrict__ candKeys,
                                            const float4* __restrict__ boxS,
                                            const float* __restrict__ maxcv,
                                            float* __restrict__ out) {
  const int b = blockIdx.x;
  const int lane = threadIdx.x;
  float* dets = out + (size_t)b * (MAXDET * 5);
  float* lbls = out + (size_t)NIMG * MAXDET * 5 + (size_t)b * MAXDET;
  for (int i = lane; i < MAXDET; i += 64) {
    dets[i * 5 + 0] = 0.f; dets[i * 5 + 1] = 0.f; dets[i * 5 + 2] = 0.f;
    dets[i * 5 + 3] = 0.f; dets[i * 5 + 4] = 0.f;
    lbls[i] = -1.0f;
  }
  __syncthreads();
  const float mc1 = __fadd_rn(maxcv[b], 1.0f);
  const unsigned long long* ck = candKeys + (size_t)b * TOPK;
  const float4* bs = boxS + (size_t)b * TOPK;
  float pbx1[2], pby1[2], pbx2[2], pby2[2], parea[2];
  int P = 0;
  bool done = false;
  for (int base = 0; base < TOPK && !done; base += 64) {
    const int e = base + lane;
    unsigned long long key = ck[e];
    float score = -INFINITY; int c = 0;
    float4 bx = bs[e];
    if (key) {
      unsigned mb = (unsigned)(key >> 32);
      score = __uint_as_float(mb ^ 0x80000000u);
      unsigned idx = 0xFFFFFFFFu - (unsigned)(key & 0xFFFFFFFFull);
      c = (int)(idx % 80u);
    }
    float off = __fmul_rn((float)c, mc1);
    float nx1 = __fadd_rn(bx.x, off), ny1 = __fadd_rn(bx.y, off);
    float nx2 = __fadd_rn(bx.z, off), ny2 = __fadd_rn(bx.w, off);
    for (int t = 0; t < 64; ++t) {
      float s_e = __shfl(score, t);
      if (!(s_e > 0.0f)) { done = true; break; }
      float ex1 = __shfl(nx1, t), ey1 = __shfl(ny1, t);
      float ex2 = __shfl(nx2, t), ey2 = __shfl(ny2, t);
      float ea = __fmul_rn(__fsub_rn(ex2, ex1), __fsub_rn(ey2, ey1));
      bool sup = false;
      #pragma unroll
      for (int k2 = 0; k2 < 2; ++k2) {
        int pi = k2 * 64 + lane;
        if (pi < P) {
          float tlx = fmaxf(pbx1[k2], ex1), tly = fmaxf(pby1[k2], ey1);
          float brx = fminf(pbx2[k2], ex2), bry = fminf(pby2[k2], ey2);
          float iw = fmaxf(__fsub_rn(brx, tlx), 0.0f);
          float ih = fmaxf(__fsub_rn(bry, tly), 0.0f);
          float inter = __fmul_rn(iw, ih);
          float denom = __fadd_rn(__fsub_rn(__fadd_rn(parea[k2], ea), inter), 1e-12f);
          float iou = __fdiv_rn(inter, denom);
          if (iou > IOU_THR) sup = true;
        }
      }
      if (!__any(sup)) {
        float cx1 = __shfl(bx.x, t), cy1 = __shfl(bx.y, t);
        float cx2 = __shfl(bx.z, t), cy2 = __shfl(bx.w, t);
        int   ce  = __shfl(c, t);
        if (lane == (P & 63)) {
          int slot = P >> 6;
          pbx1[slot] = ex1; pby1[slot] = ey1; pbx2[slot] = ex2; pby2[slot] = ey2;
          parea[slot] = ea;
        }
        if (lane == 0) {
          dets[P * 5 + 0] = cx1; dets[P * 5 + 1] = cy1;
          dets[P * 5 + 2] = cx2; dets[P * 5 + 3] = cy2;
          dets[P * 5 + 4] = s_e;
          lbls[P] = (float)ce;
        }
        ++P;
        if (P == MAXDET) { done = true; break; }
      }
    }
  }
}

// ---------------- launch -----------------------------------------------------------
extern "C" void kernel_launch(void* const* d_in, const int* in_sizes, int n_in,
                              void* d_out, int out_size, void* d_ws, size_t ws_size,
                              hipStream_t stream) {
  const float* p0 = (const float*)d_in[0];  // [16,255,19,19]
  const float* p1 = (const float*)d_in[1];  // [16,255,38,38]
  const float* p2 = (const float*)d_in[2];  // [16,255,76,76]
  float* out = (float*)d_out;
  char* ws = (char*)d_ws;

  // ws layout
  const size_t OFF_MERGED = 0;                          // 16*8192*4  = 524288
  const size_t OFF_CNT    = 524288;                     // 256 B of counters
  const size_t OFF_CK     = 524544;                     // 16*4096*8  = 524288
  const size_t OFF_BL     = 1048832;                    // 16*8192*8  = 1048576
  const size_t OFF_BOX    = 2097408;                    // 16*4096*16 = 1048576
  const size_t OFF_PRIV   = 3145984;                    // 432*8192*4 = 14155776
  const size_t NEED_PRIV  = OFF_PRIV + (size_t)NBLK * NHIST * 4;  // 17301760

  unsigned* merged = (unsigned*)(ws + OFF_MERGED);
  unsigned* candCount = (unsigned*)(ws + OFF_CNT);
  unsigned* bCount = candCount + 16;
  int* bb1 = (int*)(bCount + 16);
  float* maxcv = (float*)(bb1 + 16);
  unsigned long long* candKeys = (unsigned long long*)(ws + OFF_CK);
  unsigned long long* blist = (unsigned long long*)(ws + OFF_BL);
  float4* boxS = (float4*)(ws + OFF_BOX);
  unsigned* priv = (unsigned*)(ws + OFF_PRIV);

  const bool use_priv = ws_size >= NEED_PRIV;
  if (use_priv) {
    hipMemsetAsync(ws + OFF_CNT, 0, 256, stream);                 // counters only
    k_hist<true><<<NBLK, 256, 0, stream>>>(p0, p1, p2, priv);
    k_merge<<<dim3(NHIST / 256, NIMG), 256, 0, stream>>>(priv, merged);
  } else {
    hipMemsetAsync(ws, 0, OFF_CNT + 256, stream);                 // merged hist + counters
    k_hist<false><<<NBLK, 256, 0, stream>>>(p0, p1, p2, merged);
  }
  k_scan<<<NIMG, 256, 0, stream>>>(merged, bb1);
  k_collect<<<NBLK, 256, 0, stream>>>(p0, p1, p2, bb1, candCount, bCount, candKeys, blist);
  k_bsort<<<NIMG, 1024, 0, stream>>>(candCount, bCount, candKeys, blist);
  k_csort_decode<<<NIMG, 1024, 0, stream>>>(p0, p1, p2, candKeys, boxS, maxcv);
  k_nms<<<NIMG, 64, 0, stream>>>(candKeys, boxS, maxcv, out);
}